// Round 5
// baseline (94.368 us; speedup 1.0000x reference)
//
#include <hip/hip_runtime.h>
#include <hip/hip_bf16.h>

// SplineLoss: reference evaluates a not-a-knot cubic spline at INTEGER sample
// times t=0,10,...,8190 with knots at integers 0..8191 -> local parameter is
// exactly 0 for every sample, so the spline solve vanishes and the result is
// exactly:  mean_{b<1024, j<820} (true[b,10j] - pred[b,10j])^2
//
// Stride 40B < 64B line -> every line of both 32MB inputs is needed; minimum
// traffic 64MB, roofline ~10.2us at 6.3TB/s. Within float4 group g (t=4g),
// samples land at .x when g%5==0 and .z when g%5==2 (256 = 1 mod 5, so the
// residue advances by +1 per 256-group step).
//
// Session ledger:
//  R3: per-block agent-scope release/acq_rel fences -> +100us (L2 writebacks
//      serialized across 2048 blocks). Never again.
//  R1: 1024 same-address atomicAdds ~ +13us tail. Two-dispatch instead.
//  R4: 8 preloads/thread, 2048 one-shot blocks -> only -2us vs R2. This round
//      discriminates: 16 preloads/thread in an unrolled register array,
//      1024 blocks (4/CU exactly), 32KB/wave in flight. If dur_us doesn't
//      move, the remaining time is harness floor (ws-poison + input restore),
//      not kernel.

#define B_ROWS   1024
#define N_COLS   8192
#define N_SAMP   820
#define BLOCK    256
#define GRID     B_ROWS                    // one row per block
#define GPT      8                         // float4 groups per thread per array

__global__ __launch_bounds__(BLOCK)
void spline_partial_kernel(const float* __restrict__ tf,
                           const float* __restrict__ pf,
                           float* __restrict__ partial) {
    const int b   = blockIdx.x;
    const int tid = threadIdx.x;
    const float4* t4 = (const float4*)(tf + (size_t)b * N_COLS);
    const float4* p4 = (const float4*)(pf + (size_t)b * N_COLS);

    // ---- 16 independent global_load_dwordx4 issued before ANY use ----
    float4 a[GPT], c[GPT];
    #pragma unroll
    for (int k = 0; k < GPT; ++k) a[k] = t4[tid + BLOCK * k];
    #pragma unroll
    for (int k = 0; k < GPT; ++k) c[k] = p4[tid + BLOCK * k];

    // ---- predicated squared-diff accumulate ----
    float acc = 0.0f;
    int r = tid % 5;                       // residue of group index mod 5
    #pragma unroll
    for (int k = 0; k < GPT; ++k) {
        const float d0 = a[k].x - c[k].x;
        const float d2 = a[k].z - c[k].z;
        acc += (r == 0) ? d0 * d0 : 0.0f;
        acc += (r == 2) ? d2 * d2 : 0.0f;
        r = (r == 4) ? 0 : r + 1;          // (tid + 256(k+1)) % 5
    }

    // ---- wave-64 shuffle reduction, then cross-wave via LDS ----
    #pragma unroll
    for (int off = 32; off > 0; off >>= 1)
        acc += __shfl_down(acc, off, 64);

    __shared__ float wsum[BLOCK / 64];
    const int lane = tid & 63;
    const int wid  = tid >> 6;
    if (lane == 0) wsum[wid] = acc;
    __syncthreads();

    if (tid == 0) {
        float s = 0.0f;
        #pragma unroll
        for (int w = 0; w < BLOCK / 64; ++w) s += wsum[w];
        partial[b] = s;                    // plain store; next dispatch sees it
    }
}

__global__ __launch_bounds__(BLOCK)
void spline_final_kernel(const float* __restrict__ partial,
                         float* __restrict__ out) {
    float acc = 0.0f;
    #pragma unroll
    for (int k = 0; k < GRID / BLOCK; ++k)     // 4 coalesced loads
        acc += partial[k * BLOCK + threadIdx.x];

    #pragma unroll
    for (int off = 32; off > 0; off >>= 1)
        acc += __shfl_down(acc, off, 64);

    __shared__ float wsum[BLOCK / 64];
    const int lane = threadIdx.x & 63;
    const int wid  = threadIdx.x >> 6;
    if (lane == 0) wsum[wid] = acc;
    __syncthreads();

    if (threadIdx.x == 0) {
        float s = 0.0f;
        #pragma unroll
        for (int w = 0; w < BLOCK / 64; ++w) s += wsum[w];
        out[0] = s * (1.0f / (float)(B_ROWS * N_SAMP));  // overwrite, no memset
    }
}

extern "C" void kernel_launch(void* const* d_in, const int* in_sizes, int n_in,
                              void* d_out, int out_size, void* d_ws, size_t ws_size,
                              hipStream_t stream) {
    const float* tf = (const float*)d_in[0];   // true_frames  (1024, 8192) f32
    const float* pf = (const float*)d_in[1];   // predicted_frames
    float* out     = (float*)d_out;            // scalar f32
    float* partial = (float*)d_ws;             // 1024 floats of scratch

    spline_partial_kernel<<<GRID, BLOCK, 0, stream>>>(tf, pf, partial);
    spline_final_kernel<<<1, BLOCK, 0, stream>>>(partial, out);
}